// Round 3
// baseline (323.120 us; speedup 1.0000x reference)
//
#include <hip/hip_runtime.h>

#define N_NODES 50000
#define N_EDGES 200000
#define S_DIM   8
#define F_DIM   32      // F_IN == F == 32
#define G_SEG   512
#define P_PAIRS 1024
#define A_COLS  288     // 9 * 32 : 8 Wk rows + 1 bk row, each giving 32 outputs

// ---------------------------------------------------------------------------
// K0: zero deg[] and pooled[] (harness poisons ws with 0xAA; we own our zeros)
// ---------------------------------------------------------------------------
__global__ __launch_bounds__(256)
void zero_init(int* __restrict__ deg, float* __restrict__ pooled)
{
    const int gid = blockIdx.x * 256 + threadIdx.x;
    if (gid < N_NODES) deg[gid] = 0;
    if (gid < G_SEG * F_DIM) pooled[gid] = 0.f;
}

// K_csr1: histogram of targets
__global__ __launch_bounds__(256)
void deg_hist(const int* __restrict__ tgt, int* __restrict__ deg)
{
    const int e = blockIdx.x * 256 + threadIdx.x;
    if (e < N_EDGES) atomicAdd(&deg[tgt[e]], 1);
}

// K_csr2: exclusive prefix sum over deg -> rowstart, cursor (single block)
__global__ __launch_bounds__(1024)
void scan_deg(const int* __restrict__ deg, int* __restrict__ rowstart,
              int* __restrict__ cursor)
{
    __shared__ int psum[1024];
    const int t  = threadIdx.x;
    const int CH = (N_NODES + 1023) / 1024;   // 49
    const int base = t * CH;

    int s = 0;
    for (int i = 0; i < CH; ++i)
        if (base + i < N_NODES) s += deg[base + i];
    psum[t] = s;
    __syncthreads();
    for (int off = 1; off < 1024; off <<= 1) {
        int v = (t >= off) ? psum[t - off] : 0;
        __syncthreads();
        psum[t] += v;
        __syncthreads();
    }
    int excl = (t == 0) ? 0 : psum[t - 1];
    for (int i = 0; i < CH; ++i) {
        const int n = base + i;
        if (n < N_NODES) {
            rowstart[n] = excl;
            cursor[n]   = excl;
            excl += deg[n];
        }
    }
    if (t == 0) rowstart[N_NODES] = N_EDGES;
}

// K_csr3: scatter edge ids into CSR buckets
__global__ __launch_bounds__(256)
void csr_scatter(const int* __restrict__ tgt, int* __restrict__ cursor,
                 int* __restrict__ eid)
{
    const int e = blockIdx.x * 256 + threadIdx.x;
    if (e < N_EDGES) {
        const int pos = atomicAdd(&cursor[tgt[e]], 1);
        eid[pos] = e;
    }
}

// ---------------------------------------------------------------------------
// K1: per-node GEMM.
//   A[n][s*32+o] = sum_i h[n][i] * Wk[s][i*32+o]   (s = 0..7)
//   A[n][8*32+o] = sum_i h[n][i] * bk[i*32+o]      (bias row, e'_8 = 1)
//   agg[n][o]    = sum_i h[n][i] * root[i][o] + b[o]   (init for aggregation)
// LAYER==0: h = x[n, 0..31] (row stride 33). LAYER==1: h = relu(prev agg).
// ---------------------------------------------------------------------------
template <int LAYER>
__global__ __launch_bounds__(320)
void node_gemm(const float* __restrict__ hsrc,
               const float* __restrict__ Wk, const float* __restrict__ bk,
               const float* __restrict__ root, const float* __restrict__ bias,
               float* __restrict__ A, float* __restrict__ agg)
{
    const int NB = 64;
    __shared__ float hh[NB][F_DIM];

    const int nb   = blockIdx.x * NB;
    const int nmax = (N_NODES - nb < NB) ? (N_NODES - nb) : NB;

    if (LAYER == 0) {
        for (int idx = threadIdx.x; idx < nmax * F_DIM; idx += 320) {
            const int n = idx >> 5, i = idx & 31;
            hh[n][i] = hsrc[(size_t)(nb + n) * (F_DIM + 1) + i];
        }
    } else {
        const float4* src4 = (const float4*)(hsrc + (size_t)nb * F_DIM);
        for (int idx = threadIdx.x; idx < nmax * (F_DIM / 4); idx += 320) {
            float4 v = src4[idx];
            v.x = v.x > 0.f ? v.x : 0.f;
            v.y = v.y > 0.f ? v.y : 0.f;
            v.z = v.z > 0.f ? v.z : 0.f;
            v.w = v.w > 0.f ? v.w : 0.f;
            ((float4*)hh)[idx] = v;
        }
    }
    __syncthreads();

    const int c = threadIdx.x;        // 0..319
    float w[F_DIM];
    float init = 0.f;
    if (c < 256) {                    // Wk rows
        const int s = c >> 5, o = c & 31;
        #pragma unroll
        for (int i = 0; i < F_DIM; ++i) w[i] = Wk[s * (F_DIM * F_DIM) + i * F_DIM + o];
    } else if (c < A_COLS) {          // bk row
        const int o = c & 31;
        #pragma unroll
        for (int i = 0; i < F_DIM; ++i) w[i] = bk[i * F_DIM + o];
    } else {                          // root + bias -> agg init
        const int o = c - A_COLS;
        #pragma unroll
        for (int i = 0; i < F_DIM; ++i) w[i] = root[i * F_DIM + o];
        init = bias[o];
    }

    for (int n = 0; n < nmax; ++n) {
        const float4* hv = (const float4*)hh[n];
        float acc = init;
        #pragma unroll
        for (int i4 = 0; i4 < F_DIM / 4; ++i4) {
            float4 h4 = hv[i4];
            acc += h4.x * w[4*i4]   + h4.y * w[4*i4+1]
                 + h4.z * w[4*i4+2] + h4.w * w[4*i4+3];
        }
        if (c < A_COLS) A[(size_t)(nb + n) * A_COLS + c] = acc;
        else            agg[(size_t)(nb + n) * F_DIM + (c - A_COLS)] = acc;
    }
}

// ---------------------------------------------------------------------------
// K2: gather-side edge aggregation. One wave64 per node; lane = k*32 + o with
// k in {0,1} handling alternate incident edges. No atomics.
//   agg[n][o] += sum_{e: tgt[e]==n} ( A[src][256+o] + sum_s evec[e][s]*A[src][s*32+o] )
// ---------------------------------------------------------------------------
__global__ __launch_bounds__(256)
void edge_agg(const float* __restrict__ A, const float* __restrict__ evec,
              const int* __restrict__ src, const int* __restrict__ eid,
              const int* __restrict__ rowstart, float* __restrict__ agg)
{
    const int wave = (blockIdx.x * 256 + threadIdx.x) >> 6;   // = node
    const int lane = threadIdx.x & 63;
    if (wave >= N_NODES) return;
    const int n = wave;
    const int o = lane & 31;
    const int k = lane >> 5;

    const int r0 = rowstart[n];
    const int r1 = rowstart[n + 1];

    float acc = 0.f;
    for (int idx = r0 + k; idx < r1; idx += 2) {
        const int   e  = eid[idx];
        const int   sn = src[e];
        const float* Ap = A + (size_t)sn * A_COLS + o;
        float m = Ap[8 * F_DIM];               // bk row
        #pragma unroll
        for (int s = 0; s < S_DIM; ++s)
            m += evec[(size_t)e * S_DIM + s] * Ap[s * F_DIM];
        acc += m;
    }
    acc += __shfl_xor(acc, 32);                // combine k=0,1 halves
    if (k == 0) agg[(size_t)n * F_DIM + o] += acc;
}

// ---------------------------------------------------------------------------
// K3: pooled[seg[n]] += trunc(relu(agg2[n])). seg is SORTED -> run-based
// segmented reduction; ~65K atomics instead of 1.6M.
// Block = 256 threads = 8 rows x 32 cols; row r handles 32 contiguous nodes.
// ---------------------------------------------------------------------------
__global__ __launch_bounds__(256)
void pool_kernel(const float* __restrict__ agg2, const int* __restrict__ seg,
                 float* __restrict__ pooled)
{
    const int o    = threadIdx.x & 31;
    const int r    = threadIdx.x >> 5;               // 0..7
    const int base = blockIdx.x * 256 + r * 32;      // first node of this row

    int   curseg = -1;
    float acc    = 0.f;
    for (int i = 0; i < 32; ++i) {
        const int n = base + i;
        if (n >= N_NODES) break;
        const int sg = seg[n];
        if (sg != curseg) {
            if (curseg >= 0 && acc != 0.f)
                atomicAdd(&pooled[(size_t)curseg * F_DIM + o], acc);
            curseg = sg;
            acc = 0.f;
        }
        float v = agg2[(size_t)n * F_DIM + o];
        v = v > 0.f ? v : 0.f;
        acc += truncf(v);
    }
    if (curseg >= 0 && acc != 0.f)
        atomicAdd(&pooled[(size_t)curseg * F_DIM + o], acc);
}

// ---------------------------------------------------------------------------
// K4: out[g] = relu(pooled[g] . Wd + bd); result[p] = out[ib[p]] - out[ia[p]]
// ---------------------------------------------------------------------------
__global__ __launch_bounds__(512)
void head_kernel(const float* __restrict__ pooled, const float* __restrict__ Wd,
                 const float* __restrict__ bd, const int* __restrict__ ia,
                 const int* __restrict__ ib, float* __restrict__ out)
{
    __shared__ float og[G_SEG];
    const int g = threadIdx.x;
    if (g < G_SEG) {
        float acc = bd[0];
        #pragma unroll
        for (int i = 0; i < F_DIM; ++i) acc += pooled[(size_t)g * F_DIM + i] * Wd[i];
        og[g] = acc > 0.f ? acc : 0.f;
    }
    __syncthreads();
    for (int p = threadIdx.x; p < P_PAIRS; p += 512)
        out[p] = og[ib[p]] - og[ia[p]];
}

// ---------------------------------------------------------------------------
extern "C" void kernel_launch(void* const* d_in, const int* in_sizes, int n_in,
                              void* d_out, int out_size, void* d_ws, size_t ws_size,
                              hipStream_t stream)
{
    const float* x    = (const float*)d_in[0];
    const float* e    = (const float*)d_in[1];
    const int*   src  = (const int*)d_in[2];
    const int*   tgt  = (const int*)d_in[3];
    const int*   seg  = (const int*)d_in[4];
    const int*   ia   = (const int*)d_in[5];
    const int*   ib   = (const int*)d_in[6];
    const float* Wk1  = (const float*)d_in[7];
    const float* bk1  = (const float*)d_in[8];
    const float* root1= (const float*)d_in[9];
    const float* b1   = (const float*)d_in[10];
    const float* Wk2  = (const float*)d_in[11];
    const float* bk2  = (const float*)d_in[12];
    const float* root2= (const float*)d_in[13];
    const float* b2   = (const float*)d_in[14];
    const float* Wd   = (const float*)d_in[15];
    const float* bd   = (const float*)d_in[16];
    float* out = (float*)d_out;

    float* A      = (float*)d_ws;                       // 50000*288 f32 = 57.6 MB
    float* ag1    = A   + (size_t)N_NODES * A_COLS;     // 6.4 MB
    float* ag2    = ag1 + (size_t)N_NODES * F_DIM;      // 6.4 MB
    float* pooled = ag2 + (size_t)N_NODES * F_DIM;      // 64 KB
    int*   deg      = (int*)(pooled + (size_t)G_SEG * F_DIM);
    int*   cursor   = deg + N_NODES;
    int*   rowstart = cursor + N_NODES;                 // N_NODES+1
    int*   eid      = rowstart + (N_NODES + 1);         // N_EDGES

    const int nblk = (N_NODES + 63) / 64;
    const int eblk = (N_EDGES + 255) / 256;
    const int ablk = (N_NODES * 64 + 255) / 256;        // wave-per-node

    zero_init  <<<(N_NODES + 255) / 256, 256, 0, stream>>>(deg, pooled);
    deg_hist   <<<eblk, 256, 0, stream>>>(tgt, deg);
    scan_deg   <<<1, 1024, 0, stream>>>(deg, rowstart, cursor);
    csr_scatter<<<eblk, 256, 0, stream>>>(tgt, cursor, eid);

    node_gemm<0><<<nblk, 320, 0, stream>>>(x,   Wk1, bk1, root1, b1, A, ag1);
    edge_agg    <<<ablk, 256, 0, stream>>>(A, e, src, eid, rowstart, ag1);
    node_gemm<1><<<nblk, 320, 0, stream>>>(ag1, Wk2, bk2, root2, b2, A, ag2);
    edge_agg    <<<ablk, 256, 0, stream>>>(A, e, src, eid, rowstart, ag2);

    pool_kernel<<<(N_NODES + 255) / 256, 256, 0, stream>>>(ag2, seg, pooled);
    head_kernel<<<1, 512, 0, stream>>>(pooled, Wd, bd, ia, ib, out);
}

// Round 4
// 178.842 us; speedup vs baseline: 1.8067x; 1.8067x over previous
//
#include <hip/hip_runtime.h>

#define N_NODES 50000
#define N_EDGES 200000
#define S_DIM   8
#define F_DIM   32      // F_IN == F == 32
#define G_SEG   512
#define P_PAIRS 1024
#define A_COLS  288     // 9 * 32 : 8 Wk rows + 1 bk row, each giving 32 outputs
#define SCAN_B  196     // ceil(N_NODES / 256)

// ---------------------------------------------------------------------------
// K0: zero deg[] and pooled[]
// ---------------------------------------------------------------------------
__global__ __launch_bounds__(256)
void zero_init(int* __restrict__ deg, float* __restrict__ pooled)
{
    const int gid = blockIdx.x * 256 + threadIdx.x;
    if (gid < N_NODES) deg[gid] = 0;
    if (gid < G_SEG * F_DIM) pooled[gid] = 0.f;
}

// K_csr1: histogram of SOURCES (sorting edges by src for A-row locality)
__global__ __launch_bounds__(256)
void deg_hist(const int* __restrict__ src, int* __restrict__ deg)
{
    const int e = blockIdx.x * 256 + threadIdx.x;
    if (e < N_EDGES) atomicAdd(&deg[src[e]], 1);
}

// K_csr2a: per-block partial sums of deg
__global__ __launch_bounds__(256)
void sum_blocks(const int* __restrict__ deg, int* __restrict__ partial)
{
    __shared__ int sd[256];
    const int t = threadIdx.x;
    const int n = blockIdx.x * 256 + t;
    sd[t] = (n < N_NODES) ? deg[n] : 0;
    __syncthreads();
    for (int off = 128; off > 0; off >>= 1) {
        if (t < off) sd[t] += sd[t + off];
        __syncthreads();
    }
    if (t == 0) partial[blockIdx.x] = sd[0];
}

// K_csr2b: single-block exclusive scan of the 196 partials
__global__ __launch_bounds__(256)
void scan_partials(const int* __restrict__ partial, int* __restrict__ blockoff)
{
    __shared__ int sd[256];
    const int t = threadIdx.x;
    sd[t] = (t < SCAN_B) ? partial[t] : 0;
    __syncthreads();
    for (int off = 1; off < 256; off <<= 1) {
        int v = (t >= off) ? sd[t - off] : 0;
        __syncthreads();
        sd[t] += v;
        __syncthreads();
    }
    if (t < SCAN_B) blockoff[t] = (t == 0) ? 0 : sd[t - 1];
}

// K_csr2c: per-block local exclusive scan + blockoff -> rowstart, cursor
__global__ __launch_bounds__(256)
void write_rowstart(const int* __restrict__ deg, const int* __restrict__ blockoff,
                    int* __restrict__ rowstart, int* __restrict__ cursor)
{
    __shared__ int sd[256];
    const int t = threadIdx.x;
    const int n = blockIdx.x * 256 + t;
    const int d = (n < N_NODES) ? deg[n] : 0;
    sd[t] = d;
    __syncthreads();
    for (int off = 1; off < 256; off <<= 1) {
        int v = (t >= off) ? sd[t - off] : 0;
        __syncthreads();
        sd[t] += v;
        __syncthreads();
    }
    if (n < N_NODES) {
        const int rs = blockoff[blockIdx.x] + sd[t] - d;   // exclusive
        rowstart[n] = rs;
        cursor[n]   = rs;
    }
    if (blockIdx.x == 0 && t == 0) rowstart[N_NODES] = N_EDGES;
}

// K_csr3: scatter edges into src-sorted order, carrying src/tgt along
__global__ __launch_bounds__(256)
void csr_scatter(const int* __restrict__ src, const int* __restrict__ tgt,
                 int* __restrict__ cursor, int* __restrict__ eid,
                 int* __restrict__ srcs, int* __restrict__ tgts)
{
    const int e = blockIdx.x * 256 + threadIdx.x;
    if (e < N_EDGES) {
        const int sn  = src[e];
        const int pos = atomicAdd(&cursor[sn], 1);
        eid[pos]  = e;
        srcs[pos] = sn;
        tgts[pos] = tgt[e];
    }
}

// ---------------------------------------------------------------------------
// K1: per-node GEMM.
//   A[n][s*32+o] = sum_i h[n][i] * Wk[s][i*32+o]   (s = 0..7)
//   A[n][8*32+o] = sum_i h[n][i] * bk[i*32+o]      (bias row, e'_8 = 1)
//   agg[n][o]    = sum_i h[n][i] * root[i][o] + b[o]
// LAYER==0: h = x[n, 0..31] (row stride 33). LAYER==1: h = relu(prev agg).
// ---------------------------------------------------------------------------
template <int LAYER>
__global__ __launch_bounds__(320)
void node_gemm(const float* __restrict__ hsrc,
               const float* __restrict__ Wk, const float* __restrict__ bk,
               const float* __restrict__ root, const float* __restrict__ bias,
               float* __restrict__ A, float* __restrict__ agg)
{
    const int NB = 64;
    __shared__ float hh[NB][F_DIM];

    const int nb   = blockIdx.x * NB;
    const int nmax = (N_NODES - nb < NB) ? (N_NODES - nb) : NB;

    if (LAYER == 0) {
        for (int idx = threadIdx.x; idx < nmax * F_DIM; idx += 320) {
            const int n = idx >> 5, i = idx & 31;
            hh[n][i] = hsrc[(size_t)(nb + n) * (F_DIM + 1) + i];
        }
    } else {
        const float4* src4 = (const float4*)(hsrc + (size_t)nb * F_DIM);
        for (int idx = threadIdx.x; idx < nmax * (F_DIM / 4); idx += 320) {
            float4 v = src4[idx];
            v.x = v.x > 0.f ? v.x : 0.f;
            v.y = v.y > 0.f ? v.y : 0.f;
            v.z = v.z > 0.f ? v.z : 0.f;
            v.w = v.w > 0.f ? v.w : 0.f;
            ((float4*)hh)[idx] = v;
        }
    }
    __syncthreads();

    const int c = threadIdx.x;        // 0..319
    float w[F_DIM];
    float init = 0.f;
    if (c < 256) {                    // Wk rows
        const int s = c >> 5, o = c & 31;
        #pragma unroll
        for (int i = 0; i < F_DIM; ++i) w[i] = Wk[s * (F_DIM * F_DIM) + i * F_DIM + o];
    } else if (c < A_COLS) {          // bk row
        const int o = c & 31;
        #pragma unroll
        for (int i = 0; i < F_DIM; ++i) w[i] = bk[i * F_DIM + o];
    } else {                          // root + bias -> agg init
        const int o = c - A_COLS;
        #pragma unroll
        for (int i = 0; i < F_DIM; ++i) w[i] = root[i * F_DIM + o];
        init = bias[o];
    }

    for (int n = 0; n < nmax; ++n) {
        const float4* hv = (const float4*)hh[n];
        float acc = init;
        #pragma unroll
        for (int i4 = 0; i4 < F_DIM / 4; ++i4) {
            float4 h4 = hv[i4];
            acc += h4.x * w[4*i4]   + h4.y * w[4*i4+1]
                 + h4.z * w[4*i4+2] + h4.w * w[4*i4+3];
        }
        if (c < A_COLS) A[(size_t)(nb + n) * A_COLS + c] = acc;
        else            agg[(size_t)(nb + n) * F_DIM + (c - A_COLS)] = acc;
    }
}

// ---------------------------------------------------------------------------
// K2: edge scatter over SRC-SORTED edges. 32 lanes per edge, lane o:
//   msg[o] = A[sn][256+o] + sum_s evec[e][s] * A[sn][s*32+o]
// Consecutive edges share sn (avg out-degree 4) -> A rows hit L1/L2.
// ---------------------------------------------------------------------------
__global__ __launch_bounds__(256)
void edge_msg(const float* __restrict__ A, const float* __restrict__ evec,
              const int* __restrict__ eid, const int* __restrict__ srcs,
              const int* __restrict__ tgts, float* __restrict__ agg)
{
    const int gid = blockIdx.x * 256 + threadIdx.x;
    const int i   = gid >> 5;
    const int o   = gid & 31;
    if (i >= N_EDGES) return;

    const int e  = eid[i];
    const int sn = srcs[i];
    const int tn = tgts[i];
    const float* Ap = A + (size_t)sn * A_COLS + o;
    const float* ev = evec + (size_t)e * S_DIM;

    float msg = Ap[8 * F_DIM];            // bk row (implicit e'_8 = 1)
    #pragma unroll
    for (int s = 0; s < S_DIM; ++s)
        msg += ev[s] * Ap[s * F_DIM];

    atomicAdd(&agg[(size_t)tn * F_DIM + o], msg);
}

// ---------------------------------------------------------------------------
// K3: pooled[seg[n]] += trunc(relu(agg2[n])). seg sorted -> run-based.
// ---------------------------------------------------------------------------
__global__ __launch_bounds__(256)
void pool_kernel(const float* __restrict__ agg2, const int* __restrict__ seg,
                 float* __restrict__ pooled)
{
    const int o    = threadIdx.x & 31;
    const int r    = threadIdx.x >> 5;               // 0..7
    const int base = blockIdx.x * 256 + r * 32;      // first node of this row

    int   curseg = -1;
    float acc    = 0.f;
    for (int i = 0; i < 32; ++i) {
        const int n = base + i;
        if (n >= N_NODES) break;
        const int sg = seg[n];
        if (sg != curseg) {
            if (curseg >= 0 && acc != 0.f)
                atomicAdd(&pooled[(size_t)curseg * F_DIM + o], acc);
            curseg = sg;
            acc = 0.f;
        }
        float v = agg2[(size_t)n * F_DIM + o];
        v = v > 0.f ? v : 0.f;
        acc += truncf(v);
    }
    if (curseg >= 0 && acc != 0.f)
        atomicAdd(&pooled[(size_t)curseg * F_DIM + o], acc);
}

// ---------------------------------------------------------------------------
// K4: out[g] = relu(pooled[g] . Wd + bd); result[p] = out[ib[p]] - out[ia[p]]
// ---------------------------------------------------------------------------
__global__ __launch_bounds__(512)
void head_kernel(const float* __restrict__ pooled, const float* __restrict__ Wd,
                 const float* __restrict__ bd, const int* __restrict__ ia,
                 const int* __restrict__ ib, float* __restrict__ out)
{
    __shared__ float og[G_SEG];
    const int g = threadIdx.x;
    if (g < G_SEG) {
        float acc = bd[0];
        #pragma unroll
        for (int i = 0; i < F_DIM; ++i) acc += pooled[(size_t)g * F_DIM + i] * Wd[i];
        og[g] = acc > 0.f ? acc : 0.f;
    }
    __syncthreads();
    for (int p = threadIdx.x; p < P_PAIRS; p += 512)
        out[p] = og[ib[p]] - og[ia[p]];
}

// ---------------------------------------------------------------------------
extern "C" void kernel_launch(void* const* d_in, const int* in_sizes, int n_in,
                              void* d_out, int out_size, void* d_ws, size_t ws_size,
                              hipStream_t stream)
{
    const float* x    = (const float*)d_in[0];
    const float* e    = (const float*)d_in[1];
    const int*   src  = (const int*)d_in[2];
    const int*   tgt  = (const int*)d_in[3];
    const int*   seg  = (const int*)d_in[4];
    const int*   ia   = (const int*)d_in[5];
    const int*   ib   = (const int*)d_in[6];
    const float* Wk1  = (const float*)d_in[7];
    const float* bk1  = (const float*)d_in[8];
    const float* root1= (const float*)d_in[9];
    const float* b1   = (const float*)d_in[10];
    const float* Wk2  = (const float*)d_in[11];
    const float* bk2  = (const float*)d_in[12];
    const float* root2= (const float*)d_in[13];
    const float* b2   = (const float*)d_in[14];
    const float* Wd   = (const float*)d_in[15];
    const float* bd   = (const float*)d_in[16];
    float* out = (float*)d_out;

    float* A      = (float*)d_ws;                       // 57.6 MB
    float* ag1    = A   + (size_t)N_NODES * A_COLS;     // 6.4 MB
    float* ag2    = ag1 + (size_t)N_NODES * F_DIM;      // 6.4 MB
    float* pooled = ag2 + (size_t)N_NODES * F_DIM;      // 64 KB
    int*   deg      = (int*)(pooled + (size_t)G_SEG * F_DIM);
    int*   cursor   = deg + N_NODES;
    int*   rowstart = cursor + N_NODES;                 // N_NODES+1
    int*   partial  = rowstart + (N_NODES + 1);         // SCAN_B
    int*   blockoff = partial + SCAN_B;                 // SCAN_B
    int*   eid      = blockoff + SCAN_B;                // N_EDGES
    int*   srcs     = eid + N_EDGES;                    // N_EDGES
    int*   tgts     = srcs + N_EDGES;                   // N_EDGES

    const int nblk = (N_NODES + 63) / 64;
    const int eblk = (N_EDGES + 255) / 256;
    const int mblk = (N_EDGES * 32) / 256;

    zero_init     <<<SCAN_B, 256, 0, stream>>>(deg, pooled);
    deg_hist      <<<eblk, 256, 0, stream>>>(src, deg);
    sum_blocks    <<<SCAN_B, 256, 0, stream>>>(deg, partial);
    scan_partials <<<1, 256, 0, stream>>>(partial, blockoff);
    write_rowstart<<<SCAN_B, 256, 0, stream>>>(deg, blockoff, rowstart, cursor);
    csr_scatter   <<<eblk, 256, 0, stream>>>(src, tgt, cursor, eid, srcs, tgts);

    node_gemm<0><<<nblk, 320, 0, stream>>>(x,   Wk1, bk1, root1, b1, A, ag1);
    edge_msg    <<<mblk, 256, 0, stream>>>(A, e, eid, srcs, tgts, ag1);
    node_gemm<1><<<nblk, 320, 0, stream>>>(ag1, Wk2, bk2, root2, b2, A, ag2);
    edge_msg    <<<mblk, 256, 0, stream>>>(A, e, eid, srcs, tgts, ag2);

    pool_kernel<<<SCAN_B, 256, 0, stream>>>(ag2, seg, pooled);
    head_kernel<<<1, 512, 0, stream>>>(pooled, Wd, bd, ia, ib, out);
}